// Round 1
// baseline (129.921 us; speedup 1.0000x reference)
//
#include <hip/hip_runtime.h>
#include <hip/hip_bf16.h>

#define BETA_LOG2E 14.426950408889634f   // 10 * log2(e)
#define EPSN 1e-6f

typedef __bf16 bf16x8 __attribute__((ext_vector_type(8)));
typedef float  f32x4  __attribute__((ext_vector_type(4)));

static __device__ inline unsigned short f2bf(float f) {
    __hip_bfloat16 h = __float2bfloat16(f);
    return __builtin_bit_cast(unsigned short, h);
}
static __device__ inline float bf2f(unsigned short u) {
    unsigned int b = ((unsigned int)u) << 16;
    return __builtin_bit_cast(float, b);
}

// ---------------------------------------------------------------------------
// Kernel 1: L2-normalize over C, transpose [b][c][n] -> [b][n][c], cast bf16.
// grid 512: idx>>8 selects tensor (f0->aT / f1->bT); then b (4) x ntile (64).
// ---------------------------------------------------------------------------
__global__ __launch_bounds__(256) void k_norm_transpose(
    const float* __restrict__ f0, const float* __restrict__ f1,
    unsigned short* __restrict__ aT, unsigned short* __restrict__ bT)
{
    __shared__ unsigned short tile[256][65];  // [c][n], +1 pad (bf16 of raw vals)
    __shared__ float partial[4][64];
    __shared__ float inv_l[64];

    int idx   = blockIdx.x;
    int which = idx >> 8;
    int rem   = idx & 255;
    int b     = rem >> 6;
    int n0    = (rem & 63) * 64;
    const float* src = which ? f1 : f0;
    unsigned short* dst = which ? bT : aT;

    int t   = threadIdx.x;
    int n_l = t & 63;
    int cg  = t >> 6;

    float ss = 0.f;
#pragma unroll 4
    for (int i = 0; i < 64; ++i) {
        int c = i * 4 + cg;
        float v = src[(b * 256 + c) * 4096 + n0 + n_l];   // coalesced over n
        ss += v * v;
        tile[c][n_l] = f2bf(v);
    }
    partial[cg][n_l] = ss;
    __syncthreads();
    if (t < 64) {
        float s = partial[0][t] + partial[1][t] + partial[2][t] + partial[3][t];
        inv_l[t] = 1.0f / fmaxf(sqrtf(s), EPSN);
    }
    __syncthreads();

    // write [n][c] bf16, 4 channels (8B) per thread per iter
#pragma unroll 4
    for (int j = 0; j < 16; ++j) {
        int nw = (t & 3) + (j & 3) * 4 + (t >> 6) * 16;
        int u  = ((t >> 2) & 15) + (j >> 2) * 16;
        int c  = u * 4;
        float inv = inv_l[nw];
        unsigned short o0 = f2bf(bf2f(tile[c + 0][nw]) * inv);
        unsigned short o1 = f2bf(bf2f(tile[c + 1][nw]) * inv);
        unsigned short o2 = f2bf(bf2f(tile[c + 2][nw]) * inv);
        unsigned short o3 = f2bf(bf2f(tile[c + 3][nw]) * inv);
        uint2 val;
        val.x = (unsigned int)o0 | ((unsigned int)o1 << 16);
        val.y = (unsigned int)o2 | ((unsigned int)o3 << 16);
        *reinterpret_cast<uint2*>(&dst[((size_t)(b * 4096 + n0 + nw)) * 256 + c]) = val;
    }
}

// ---------------------------------------------------------------------------
// Kernel 2: flash cosine-sim + online (fixed-offset) softmax stats.
// 512 blocks = 4 batch x 32 qtile(128q) x 4 keysplit(1024k). 4 waves/block,
// 32 queries/wave resident as A-fragments; keys staged in LDS (544B stride).
// stats[q][ks] = {Z, Sx, Sy, Pmax}
// ---------------------------------------------------------------------------
__global__ __launch_bounds__(256) void k_flash(
    const unsigned short* __restrict__ aT, const unsigned short* __restrict__ bT,
    float* __restrict__ stats)
{
    __shared__ unsigned short kbuf[64 * 272];  // 64 keys x 272 halfwords (544 B)

    int idx   = blockIdx.x;
    int xcd   = idx & 7;                 // XCD swizzle: batch -> 2 XCDs (L2 locality)
    int batch = xcd >> 1;
    int sub   = ((idx >> 3) << 1) | (xcd & 1);   // [0,128)
    int qt    = sub >> 2;                // [0,32)
    int ks    = sub & 3;                 // [0,4)

    int t    = threadIdx.x;
    int w    = t >> 6;
    int lane = t & 63;
    int quad = lane >> 4;
    int l15  = lane & 15;
    int q0w  = qt * 128 + w * 32;
    int k0   = ks * 1024;

    // resident A fragments: 2 strips of 16 queries x 8 K-steps
    bf16x8 afrag[2][8];
#pragma unroll
    for (int s = 0; s < 2; ++s) {
        const unsigned short* ap =
            aT + ((size_t)(batch * 4096 + q0w + s * 16 + l15)) * 256 + quad * 8;
#pragma unroll
        for (int kk = 0; kk < 8; ++kk)
            afrag[s][kk] = *reinterpret_cast<const bf16x8*>(ap + kk * 32);
    }

    float Z[8], Sx[8], Sy[8], Pm[8];
#pragma unroll
    for (int i = 0; i < 8; ++i) { Z[i] = 0.f; Sx[i] = 0.f; Sy[i] = 0.f; Pm[i] = 0.f; }

    for (int ch = 0; ch < 16; ++ch) {
        int kbase = k0 + ch * 64;
        const unsigned short* gsrc = bT + ((size_t)(batch * 4096 + kbase)) * 256;
        // stage 64 keys x 512B -> LDS with 544B row stride (bank-balanced)
#pragma unroll
        for (int i = 0; i < 8; ++i) {
            int h = i * 2048 + t * 8;                      // halfword idx in chunk
            uint4 v = *reinterpret_cast<const uint4*>(gsrc + h);
            int key  = i * 8 + (t >> 5);
            int gran = t & 31;
            *reinterpret_cast<uint4*>(&kbuf[key * 272 + gran * 8]) = v;
        }
        __syncthreads();

#pragma unroll
        for (int nt = 0; nt < 4; ++nt) {
            f32x4 acc0 = {0.f, 0.f, 0.f, 0.f};
            f32x4 acc1 = {0.f, 0.f, 0.f, 0.f};
            const unsigned short* lp = &kbuf[(nt * 16 + l15) * 272 + quad * 8];
#pragma unroll
            for (int kk = 0; kk < 8; ++kk) {
                bf16x8 bfrag = *reinterpret_cast<const bf16x8*>(lp + kk * 32);
                acc0 = __builtin_amdgcn_mfma_f32_16x16x32_bf16(afrag[0][kk], bfrag, acc0, 0, 0, 0);
                acc1 = __builtin_amdgcn_mfma_f32_16x16x32_bf16(afrag[1][kk], bfrag, acc1, 0, 0, 0);
            }
            int key  = kbase + nt * 16 + l15;   // C/D col = lane&15 = key
            float kx = (float)(key & 63);
            float ky = (float)(key >> 6);
#pragma unroll
            for (int r = 0; r < 4; ++r) {
                float p0 = exp2f(acc0[r] * BETA_LOG2E);
                Z[r]  += p0;  Sx[r] += p0 * kx;  Sy[r] += p0 * ky;
                Pm[r] = fmaxf(Pm[r], p0);
                float p1 = exp2f(acc1[r] * BETA_LOG2E);
                Z[4 + r]  += p1;  Sx[4 + r] += p1 * kx;  Sy[4 + r] += p1 * ky;
                Pm[4 + r] = fmaxf(Pm[4 + r], p1);
            }
        }
        __syncthreads();
    }

    // reduce across the 16 col-lanes (low 4 lane bits)
#pragma unroll
    for (int i = 0; i < 8; ++i) {
#pragma unroll
        for (int m = 1; m <= 8; m <<= 1) {
            Z[i]  += __shfl_xor(Z[i], m);
            Sx[i] += __shfl_xor(Sx[i], m);
            Sy[i] += __shfl_xor(Sy[i], m);
            Pm[i]  = fmaxf(Pm[i], __shfl_xor(Pm[i], m));
        }
    }
    if (l15 == 0) {
#pragma unroll
        for (int s = 0; s < 2; ++s)
#pragma unroll
            for (int r = 0; r < 4; ++r) {
                int q = q0w + s * 16 + quad * 4 + r;   // C/D row = quad*4+reg
                f32x4 st = {Z[s * 4 + r], Sx[s * 4 + r], Sy[s * 4 + r], Pm[s * 4 + r]};
                *reinterpret_cast<f32x4*>(&stats[((size_t)(batch * 4096 + q) * 4 + ks) * 4]) = st;
            }
    }
}

// ---------------------------------------------------------------------------
// Kernel 3: merge key-splits, write warp (x,y interleaved) then cert.
// ---------------------------------------------------------------------------
__global__ __launch_bounds__(256) void k_finalize(
    const float* __restrict__ stats, float* __restrict__ out)
{
    int q = blockIdx.x * 256 + threadIdx.x;   // [0, 16384)
    const f32x4* s = reinterpret_cast<const f32x4*>(stats + (size_t)q * 16);
    f32x4 a0 = s[0], a1 = s[1], a2 = s[2], a3 = s[3];
    float Z  = a0.x + a1.x + a2.x + a3.x;
    float Sx = a0.y + a1.y + a2.y + a3.y;
    float Sy = a0.z + a1.z + a2.z + a3.z;
    float Pm = fmaxf(fmaxf(a0.w, a1.w), fmaxf(a2.w, a3.w));
    float invZ = 1.0f / Z;
    out[q * 2 + 0]  = Sx * invZ;
    out[q * 2 + 1]  = Sy * invZ;
    out[32768 + q]  = Pm * invZ;
}

extern "C" void kernel_launch(void* const* d_in, const int* in_sizes, int n_in,
                              void* d_out, int out_size, void* d_ws, size_t ws_size,
                              hipStream_t stream)
{
    const float* f0 = (const float*)d_in[0];
    const float* f1 = (const float*)d_in[1];
    unsigned short* aT = (unsigned short*)d_ws;          // 4*4096*256 bf16 = 8 MB
    unsigned short* bT = aT + (size_t)4 * 4096 * 256;    // 8 MB
    float* stats = (float*)(bT + (size_t)4 * 4096 * 256);// 16384*4*4 f32 = 1 MB
    float* out = (float*)d_out;

    hipLaunchKernelGGL(k_norm_transpose, dim3(512), dim3(256), 0, stream, f0, f1, aT, bT);
    hipLaunchKernelGGL(k_flash,          dim3(512), dim3(256), 0, stream, aT, bT, stats);
    hipLaunchKernelGGL(k_finalize,       dim3(64),  dim3(256), 0, stream, stats, out);
}